// Round 1
// baseline (773.757 us; speedup 1.0000x reference)
//
#include <hip/hip_runtime.h>
#include <math.h>

#define N_NODES 50000
#define E_TRAIN 800000
#define E_POS 200000
#define E_NEG 200000

// ---------------- degree / CSR build ----------------

__global__ void count_kernel(const int* __restrict__ dst, int* __restrict__ cnt, int e) {
    int i = blockIdx.x * blockDim.x + threadIdx.x;
    if (i < e) atomicAdd(&cnt[dst[i]], 1);
}

__global__ void dis_kernel(const int* __restrict__ cnt, float* __restrict__ dis, int n) {
    int i = blockIdx.x * blockDim.x + threadIdx.x;
    if (i < n) dis[i] = 1.0f / sqrtf((float)(cnt[i] + 1));  // +1 self loop, deg>=1
}

// block-level exclusive scan (256/block) + block sums
__global__ void scan1_kernel(const int* __restrict__ cnt, int* __restrict__ offs,
                             int* __restrict__ bsum, int n) {
    __shared__ int s[256];
    int i = blockIdx.x * 256 + threadIdx.x;
    int c = (i < n) ? cnt[i] : 0;
    s[threadIdx.x] = c;
    __syncthreads();
    for (int d = 1; d < 256; d <<= 1) {
        int t = 0;
        if ((int)threadIdx.x >= d) t = s[threadIdx.x - d];
        __syncthreads();
        if ((int)threadIdx.x >= d) s[threadIdx.x] += t;
        __syncthreads();
    }
    if (i < n) offs[i] = s[threadIdx.x] - c;  // exclusive
    if (threadIdx.x == 255) bsum[blockIdx.x] = s[255];
}

__global__ void scan2_kernel(int* __restrict__ bsum, int nb) {
    if (threadIdx.x == 0 && blockIdx.x == 0) {
        int run = 0;
        for (int i = 0; i < nb; i++) { int c = bsum[i]; bsum[i] = run; run += c; }
    }
}

__global__ void scan3_kernel(int* __restrict__ offs, const int* __restrict__ bsum,
                             int* __restrict__ cursor, int n) {
    int i = blockIdx.x * 256 + threadIdx.x;   // blockDim must be 256
    if (i < n) { int o = offs[i] + bsum[i >> 8]; offs[i] = o; cursor[i] = o; }
}

__global__ void fill_kernel(const int* __restrict__ src, const int* __restrict__ dst,
                            int* __restrict__ cursor, int* __restrict__ csr_src, int e) {
    int i = blockIdx.x * blockDim.x + threadIdx.x;
    if (i < e) {
        int p = atomicAdd(&cursor[dst[i]], 1);
        csr_src[p] = src[i];
    }
}

// ---------------- fp32 tiled GEMM: C[M,N] = A[M,K] @ B[K,N] ----------------
// BM=BN=64, BK=32, 256 threads, 4x4 microtile. N multiple of 64, K multiple of 32.

__global__ __launch_bounds__(256) void gemm_kernel(
        const float* __restrict__ A, const float* __restrict__ B,
        float* __restrict__ C, int M, int N, int K) {
    __shared__ float As[32][65];
    __shared__ float Bs[32][65];
    int tid = threadIdx.x;
    int brow = blockIdx.x * 64;
    int bcol = blockIdx.y * 64;
    int tx = tid & 15, ty = tid >> 4;
    float acc[4][4] = {};
    for (int k0 = 0; k0 < K; k0 += 32) {
        #pragma unroll
        for (int i = 0; i < 8; i++) {
            int idx = tid + i * 256;           // 0..2047
            int r = idx >> 5;                  // row in tile (0..63)
            int kk = idx & 31;
            int row = brow + r;
            As[kk][r] = (row < M) ? A[(size_t)row * K + k0 + kk] : 0.f;
        }
        #pragma unroll
        for (int i = 0; i < 8; i++) {
            int idx = tid + i * 256;
            int kk = idx >> 6;                 // 0..31
            int c = idx & 63;
            Bs[kk][c] = B[(size_t)(k0 + kk) * N + bcol + c];
        }
        __syncthreads();
        #pragma unroll
        for (int kk = 0; kk < 32; kk++) {
            float a[4], b[4];
            #pragma unroll
            for (int i = 0; i < 4; i++) a[i] = As[kk][ty * 4 + i];
            #pragma unroll
            for (int j = 0; j < 4; j++) b[j] = Bs[kk][tx * 4 + j];
            #pragma unroll
            for (int i = 0; i < 4; i++)
                #pragma unroll
                for (int j = 0; j < 4; j++) acc[i][j] += a[i] * b[j];
        }
        __syncthreads();
    }
    #pragma unroll
    for (int i = 0; i < 4; i++) {
        int row = brow + ty * 4 + i;
        if (row < M) {
            #pragma unroll
            for (int j = 0; j < 4; j++)
                C[(size_t)row * N + bcol + tx * 4 + j] = acc[i][j];
        }
    }
}

// ---------------- aggregation: out[v] = sum_in h[u]*dis[u]*dis[v] + h[v]*dis[v]^2 + b ----------------
// one wave per node, lane = feature (VPT features per lane)

template<int F, bool RELU>
__global__ void aggregate_kernel(const float* __restrict__ xw,
                                 float* __restrict__ out,
                                 const float* __restrict__ dis,
                                 const int* __restrict__ starts,
                                 const int* __restrict__ ends,
                                 const int* __restrict__ csr_src,
                                 const float* __restrict__ bias,
                                 int n) {
    int wave = (blockIdx.x * blockDim.x + threadIdx.x) >> 6;
    int lane = threadIdx.x & 63;
    if (wave >= n) return;
    int v = wave;
    constexpr int VPT = F / 64;
    float dv = dis[v];
    float acc[VPT];
    #pragma unroll
    for (int i = 0; i < VPT; i++)
        acc[i] = xw[(size_t)v * F + lane + i * 64] * dv * dv;
    int s = starts[v], e = ends[v];
    for (int p = s; p < e; p++) {
        int u = csr_src[p];
        float w = dis[u] * dv;
        #pragma unroll
        for (int i = 0; i < VPT; i++)
            acc[i] += xw[(size_t)u * F + lane + i * 64] * w;
    }
    #pragma unroll
    for (int i = 0; i < VPT; i++) {
        float r = acc[i] + bias[lane + i * 64];
        if (RELU) r = fmaxf(r, 0.f);
        out[(size_t)v * F + lane + i * 64] = r;
    }
}

// ---------------- edge dot products: out[e] = h[i0] . h[i1], F=64 ----------------

__global__ void dot_kernel(const float* __restrict__ h,
                           const int* __restrict__ pos, const int* __restrict__ neg,
                           float* __restrict__ out) {
    int w = (blockIdx.x * blockDim.x + threadIdx.x) >> 6;
    int lane = threadIdx.x & 63;
    if (w >= E_POS + E_NEG) return;
    int i0, i1;
    if (w < E_POS) { i0 = pos[w]; i1 = pos[E_POS + w]; }
    else { int e = w - E_POS; i0 = neg[e]; i1 = neg[E_NEG + e]; }
    float v = h[(size_t)i0 * 64 + lane] * h[(size_t)i1 * 64 + lane];
    #pragma unroll
    for (int d = 32; d > 0; d >>= 1) v += __shfl_down(v, d);
    if (lane == 0) out[w] = v;
}

// ---------------- launch ----------------

extern "C" void kernel_launch(void* const* d_in, const int* in_sizes, int n_in,
                              void* d_out, int out_size, void* d_ws, size_t ws_size,
                              hipStream_t stream) {
    const float* x  = (const float*)d_in[0];
    const int* tei  = (const int*)d_in[1];
    const int* pos  = (const int*)d_in[2];
    const int* neg  = (const int*)d_in[3];
    const float* W1 = (const float*)d_in[4];
    const float* b1 = (const float*)d_in[5];
    const float* W2 = (const float*)d_in[6];
    const float* b2 = (const float*)d_in[7];
    const float* W3 = (const float*)d_in[8];
    const float* b3 = (const float*)d_in[9];
    float* out = (float*)d_out;

    const int* src = tei;
    const int* dst = tei + E_TRAIN;

    char* ws = (char*)d_ws;
    size_t off = 0;
    auto alloc = [&](size_t bytes) -> void* {
        void* p = ws + off;
        off = (off + bytes + 255) & ~(size_t)255;
        return p;
    };
    float* bufA = (float*)alloc((size_t)N_NODES * 256 * 4);  // xw scratch
    float* bufB = (float*)alloc((size_t)N_NODES * 256 * 4);  // h1 / h3
    float* bufC = (float*)alloc((size_t)N_NODES * 128 * 4);  // h2
    float* dis  = (float*)alloc(N_NODES * 4);
    int* cnt    = (int*)alloc(N_NODES * 4);
    int* offs   = (int*)alloc(N_NODES * 4);
    int* cursor = (int*)alloc(N_NODES * 4);
    int* bsum   = (int*)alloc(256 * 4);
    int* csr    = (int*)alloc((size_t)E_TRAIN * 4);
    (void)ws_size; (void)n_in; (void)in_sizes; (void)out_size;

    hipMemsetAsync(cnt, 0, N_NODES * 4, stream);
    count_kernel<<<(E_TRAIN + 255) / 256, 256, 0, stream>>>(dst, cnt, E_TRAIN);
    dis_kernel<<<(N_NODES + 255) / 256, 256, 0, stream>>>(cnt, dis, N_NODES);
    int nb = (N_NODES + 255) / 256;  // 196
    scan1_kernel<<<nb, 256, 0, stream>>>(cnt, offs, bsum, N_NODES);
    scan2_kernel<<<1, 64, 0, stream>>>(bsum, nb);
    scan3_kernel<<<nb, 256, 0, stream>>>(offs, bsum, cursor, N_NODES);
    fill_kernel<<<(E_TRAIN + 255) / 256, 256, 0, stream>>>(src, dst, cursor, csr, E_TRAIN);
    // after fill: offs[v] = start, cursor[v] = end

    const int MB = (N_NODES + 63) / 64;       // 782 row tiles
    const int AGG_BLOCKS = (N_NODES + 3) / 4; // 4 waves/block, 1 node/wave

    // layer 1: x[50000,128] @ W1[128,256] -> relu(agg)
    gemm_kernel<<<dim3(MB, 4), 256, 0, stream>>>(x, W1, bufA, N_NODES, 256, 128);
    aggregate_kernel<256, true><<<AGG_BLOCKS, 256, 0, stream>>>(
        bufA, bufB, dis, offs, cursor, csr, b1, N_NODES);

    // layer 2: h1[50000,256] @ W2[256,128] -> relu(agg)
    gemm_kernel<<<dim3(MB, 2), 256, 0, stream>>>(bufB, W2, bufA, N_NODES, 128, 256);
    aggregate_kernel<128, true><<<AGG_BLOCKS, 256, 0, stream>>>(
        bufA, bufC, dis, offs, cursor, csr, b2, N_NODES);

    // layer 3: h2[50000,128] @ W3[128,64] -> agg (no relu)
    gemm_kernel<<<dim3(MB, 1), 256, 0, stream>>>(bufC, W3, bufA, N_NODES, 64, 128);
    aggregate_kernel<64, false><<<AGG_BLOCKS, 256, 0, stream>>>(
        bufA, bufB, dis, offs, cursor, csr, b3, N_NODES);

    // edge dots over h3 (64 features)
    dot_kernel<<<(E_POS + E_NEG + 3) / 4, 256, 0, stream>>>(bufB, pos, neg, out);
}

// Round 2
// 606.861 us; speedup vs baseline: 1.2750x; 1.2750x over previous
//
#include <hip/hip_runtime.h>
#include <math.h>

#define N_NODES 50000
#define E_TRAIN 800000
#define E_POS 200000
#define E_NEG 200000

// ---------------- degree / CSR build ----------------

__global__ void count_kernel(const int* __restrict__ dst, int* __restrict__ cnt, int e) {
    int i = blockIdx.x * blockDim.x + threadIdx.x;
    if (i < e) atomicAdd(&cnt[dst[i]], 1);
}

__global__ void dis_kernel(const int* __restrict__ cnt, float* __restrict__ dis, int n) {
    int i = blockIdx.x * blockDim.x + threadIdx.x;
    if (i < n) dis[i] = 1.0f / sqrtf((float)(cnt[i] + 1));  // +1 self loop, deg>=1
}

// block-level exclusive scan (256/block) + block sums
__global__ void scan1_kernel(const int* __restrict__ cnt, int* __restrict__ offs,
                             int* __restrict__ bsum, int n) {
    __shared__ int s[256];
    int i = blockIdx.x * 256 + threadIdx.x;
    int c = (i < n) ? cnt[i] : 0;
    s[threadIdx.x] = c;
    __syncthreads();
    for (int d = 1; d < 256; d <<= 1) {
        int t = 0;
        if ((int)threadIdx.x >= d) t = s[threadIdx.x - d];
        __syncthreads();
        if ((int)threadIdx.x >= d) s[threadIdx.x] += t;
        __syncthreads();
    }
    if (i < n) offs[i] = s[threadIdx.x] - c;  // exclusive
    if (threadIdx.x == 255) bsum[blockIdx.x] = s[255];
}

// parallel exclusive scan of the 196 block sums (single 256-thread block)
__global__ void scan2_kernel(int* __restrict__ bsum, int nb) {
    __shared__ int s[256];
    int t = threadIdx.x;
    int v = (t < nb) ? bsum[t] : 0;
    s[t] = v;
    __syncthreads();
    for (int d = 1; d < 256; d <<= 1) {
        int u = 0;
        if (t >= d) u = s[t - d];
        __syncthreads();
        if (t >= d) s[t] += u;
        __syncthreads();
    }
    if (t < nb) bsum[t] = s[t] - v;  // exclusive
}

__global__ void scan3_kernel(int* __restrict__ offs, const int* __restrict__ bsum,
                             int* __restrict__ cursor, int n) {
    int i = blockIdx.x * 256 + threadIdx.x;   // blockDim must be 256
    if (i < n) { int o = offs[i] + bsum[i >> 8]; offs[i] = o; cursor[i] = o; }
}

__global__ void fill_kernel(const int* __restrict__ src, const int* __restrict__ dst,
                            int* __restrict__ cursor, int* __restrict__ csr_src, int e) {
    int i = blockIdx.x * blockDim.x + threadIdx.x;
    if (i < e) {
        int p = atomicAdd(&cursor[dst[i]], 1);
        csr_src[p] = src[i];
    }
}

// ---------------- fp32 tiled GEMM: C[M,N] = A[M,K] @ B[K,N] ----------------
// BM=128, BN=64, BK=32, 256 threads, 8x4 microtile.
// Requires: N % 64 == 0, K % 32 == 0. M guarded.
// BR: fused bias + relu epilogue.

template<bool BR>
__global__ __launch_bounds__(256) void gemm_kernel(
        const float* __restrict__ A, const float* __restrict__ B,
        const float* __restrict__ bias, float* __restrict__ C,
        int M, int N, int K) {
    __shared__ float As[32][132];   // transposed A tile: As[k][m], stride 132 keeps 16B align
    __shared__ float Bs[32][68];    // Bs[k][n]
    int tid = threadIdx.x;
    int brow = blockIdx.x * 128;
    int bcol = blockIdx.y * 64;
    int tx = tid & 15;              // 16 columns of 4
    int ty = tid >> 4;              // 16 rows of 8
    float acc[8][4] = {};

    for (int k0 = 0; k0 < K; k0 += 32) {
        // A tile: 128 rows x 32 k. Each thread: float4 per pass, 4 passes.
        #pragma unroll
        for (int p = 0; p < 4; p++) {
            int r = (tid >> 3) + p * 32;        // 0..127
            int kk = (tid & 7) * 4;             // 0,4,..28
            int row = brow + r;
            float4 v = make_float4(0.f, 0.f, 0.f, 0.f);
            if (row < M) v = *(const float4*)&A[(size_t)row * K + k0 + kk];
            As[kk + 0][r] = v.x;
            As[kk + 1][r] = v.y;
            As[kk + 2][r] = v.z;
            As[kk + 3][r] = v.w;
        }
        // B tile: 32 k x 64 n. Each thread: float4 per pass, 2 passes.
        #pragma unroll
        for (int p = 0; p < 2; p++) {
            int idx = p * 1024 + tid * 4;
            int kk = idx >> 6;                  // 0..31
            int c = idx & 63;
            *(float4*)&Bs[kk][c] = *(const float4*)&B[(size_t)(k0 + kk) * N + bcol + c];
        }
        __syncthreads();
        #pragma unroll
        for (int kk = 0; kk < 32; kk++) {
            float a[8], b[4];
            *(float4*)&a[0] = *(const float4*)&As[kk][ty * 8];
            *(float4*)&a[4] = *(const float4*)&As[kk][ty * 8 + 4];
            *(float4*)&b[0] = *(const float4*)&Bs[kk][tx * 4];
            #pragma unroll
            for (int i = 0; i < 8; i++)
                #pragma unroll
                for (int j = 0; j < 4; j++) acc[i][j] += a[i] * b[j];
        }
        __syncthreads();
    }

    float bv[4];
    #pragma unroll
    for (int j = 0; j < 4; j++) bv[j] = BR ? bias[bcol + tx * 4 + j] : 0.f;
    #pragma unroll
    for (int i = 0; i < 8; i++) {
        int row = brow + ty * 8 + i;
        if (row < M) {
            float4 r;
            float t0 = acc[i][0], t1 = acc[i][1], t2 = acc[i][2], t3 = acc[i][3];
            if (BR) {
                t0 = fmaxf(t0 + bv[0], 0.f);
                t1 = fmaxf(t1 + bv[1], 0.f);
                t2 = fmaxf(t2 + bv[2], 0.f);
                t3 = fmaxf(t3 + bv[3], 0.f);
            }
            r.x = t0; r.y = t1; r.z = t2; r.w = t3;
            *(float4*)&C[(size_t)row * N + bcol + tx * 4] = r;
        }
    }
}

// ---------------- aggregation: out[v] = sum_in h[u]*dis[u]*dis[v] + h[v]*dis[v]^2 (+ b, relu) ----
// one wave per node, lane = feature (VPT features per lane)

template<int F, bool RELU, bool BIAS>
__global__ void aggregate_kernel(const float* __restrict__ xw,
                                 float* __restrict__ out,
                                 const float* __restrict__ dis,
                                 const int* __restrict__ starts,
                                 const int* __restrict__ ends,
                                 const int* __restrict__ csr_src,
                                 const float* __restrict__ bias,
                                 int n) {
    int wave = (blockIdx.x * blockDim.x + threadIdx.x) >> 6;
    int lane = threadIdx.x & 63;
    if (wave >= n) return;
    int v = wave;
    constexpr int VPT = F / 64;
    float dv = dis[v];
    float acc[VPT];
    #pragma unroll
    for (int i = 0; i < VPT; i++)
        acc[i] = xw[(size_t)v * F + lane + i * 64] * dv * dv;
    int s = starts[v], e = ends[v];
    for (int p = s; p < e; p++) {
        int u = csr_src[p];
        float w = dis[u] * dv;
        #pragma unroll
        for (int i = 0; i < VPT; i++)
            acc[i] += xw[(size_t)u * F + lane + i * 64] * w;
    }
    #pragma unroll
    for (int i = 0; i < VPT; i++) {
        float r = acc[i];
        if (BIAS) r += bias[lane + i * 64];
        if (RELU) r = fmaxf(r, 0.f);
        out[(size_t)v * F + lane + i * 64] = r;
    }
}

// ---------------- edge dot products: out[e] = h[i0] . h[i1], F=64 ----------------

__global__ void dot_kernel(const float* __restrict__ h,
                           const int* __restrict__ pos, const int* __restrict__ neg,
                           float* __restrict__ out) {
    int w = (blockIdx.x * blockDim.x + threadIdx.x) >> 6;
    int lane = threadIdx.x & 63;
    if (w >= E_POS + E_NEG) return;
    int i0, i1;
    if (w < E_POS) { i0 = pos[w]; i1 = pos[E_POS + w]; }
    else { int e = w - E_POS; i0 = neg[e]; i1 = neg[E_NEG + e]; }
    float v = h[(size_t)i0 * 64 + lane] * h[(size_t)i1 * 64 + lane];
    #pragma unroll
    for (int d = 32; d > 0; d >>= 1) v += __shfl_down(v, d);
    if (lane == 0) out[w] = v;
}

// ---------------- launch ----------------

extern "C" void kernel_launch(void* const* d_in, const int* in_sizes, int n_in,
                              void* d_out, int out_size, void* d_ws, size_t ws_size,
                              hipStream_t stream) {
    const float* x  = (const float*)d_in[0];
    const int* tei  = (const int*)d_in[1];
    const int* pos  = (const int*)d_in[2];
    const int* neg  = (const int*)d_in[3];
    const float* W1 = (const float*)d_in[4];
    const float* b1 = (const float*)d_in[5];
    const float* W2 = (const float*)d_in[6];
    const float* b2 = (const float*)d_in[7];
    const float* W3 = (const float*)d_in[8];
    const float* b3 = (const float*)d_in[9];
    float* out = (float*)d_out;

    const int* src = tei;
    const int* dst = tei + E_TRAIN;

    char* ws = (char*)d_ws;
    size_t off = 0;
    auto alloc = [&](size_t bytes) -> void* {
        void* p = ws + off;
        off = (off + bytes + 255) & ~(size_t)255;
        return p;
    };
    float* bufA = (float*)alloc((size_t)N_NODES * 128 * 4);  // aggX / xw2 / xw3
    float* bufB = (float*)alloc((size_t)N_NODES * 256 * 4);  // h1, later h3
    float* bufC = (float*)alloc((size_t)N_NODES * 128 * 4);  // h2
    float* dis  = (float*)alloc(N_NODES * 4);
    int* cnt    = (int*)alloc(N_NODES * 4);
    int* offs   = (int*)alloc(N_NODES * 4);
    int* cursor = (int*)alloc(N_NODES * 4);
    int* bsum   = (int*)alloc(256 * 4);
    int* csr    = (int*)alloc((size_t)E_TRAIN * 4);
    (void)ws_size; (void)n_in; (void)in_sizes; (void)out_size;

    hipMemsetAsync(cnt, 0, N_NODES * 4, stream);
    count_kernel<<<(E_TRAIN + 255) / 256, 256, 0, stream>>>(dst, cnt, E_TRAIN);
    dis_kernel<<<(N_NODES + 255) / 256, 256, 0, stream>>>(cnt, dis, N_NODES);
    int nb = (N_NODES + 255) / 256;  // 196
    scan1_kernel<<<nb, 256, 0, stream>>>(cnt, offs, bsum, N_NODES);
    scan2_kernel<<<1, 256, 0, stream>>>(bsum, nb);
    scan3_kernel<<<nb, 256, 0, stream>>>(offs, bsum, cursor, N_NODES);
    fill_kernel<<<(E_TRAIN + 255) / 256, 256, 0, stream>>>(src, dst, cursor, csr, E_TRAIN);
    // after fill: offs[v] = start, cursor[v] = end

    const int MB = (N_NODES + 127) / 128;     // 391 row tiles
    const int AGG_BLOCKS = (N_NODES + 3) / 4; // 4 waves/block, 1 node/wave

    // layer 1 (agg-first): aggX = agg(x) [F=128]; h1 = relu(aggX @ W1 + b1) [256]
    aggregate_kernel<128, false, false><<<AGG_BLOCKS, 256, 0, stream>>>(
        x, bufA, dis, offs, cursor, csr, nullptr, N_NODES);
    gemm_kernel<true><<<dim3(MB, 4), 256, 0, stream>>>(
        bufA, W1, b1, bufB, N_NODES, 256, 128);

    // layer 2 (gemm-first): xw2 = h1 @ W2 [128]; h2 = relu(agg(xw2) + b2)
    gemm_kernel<false><<<dim3(MB, 2), 256, 0, stream>>>(
        bufB, W2, nullptr, bufA, N_NODES, 128, 256);
    aggregate_kernel<128, true, true><<<AGG_BLOCKS, 256, 0, stream>>>(
        bufA, bufC, dis, offs, cursor, csr, b2, N_NODES);

    // layer 3 (gemm-first): xw3 = h2 @ W3 [64]; h3 = agg(xw3) + b3
    gemm_kernel<false><<<dim3(MB, 1), 256, 0, stream>>>(
        bufC, W3, nullptr, bufA, N_NODES, 64, 128);
    aggregate_kernel<64, false, true><<<AGG_BLOCKS, 256, 0, stream>>>(
        bufA, bufB, dis, offs, cursor, csr, b3, N_NODES);

    // edge dots over h3 (64 features)
    dot_kernel<<<(E_POS + E_NEG + 3) / 4, 256, 0, stream>>>(bufB, pos, neg, out);
}

// Round 3
// 498.539 us; speedup vs baseline: 1.5521x; 1.2173x over previous
//
#include <hip/hip_runtime.h>
#include <math.h>

#define N_NODES 50000
#define E_TRAIN 800000
#define E_POS 200000
#define E_NEG 200000

// ---------------- degree / CSR build ----------------

__global__ void count_kernel(const int* __restrict__ dst, int* __restrict__ cnt, int e) {
    int i = blockIdx.x * blockDim.x + threadIdx.x;
    if (i < e) atomicAdd(&cnt[dst[i]], 1);
}

__global__ void dis_kernel(const int* __restrict__ cnt, float* __restrict__ dis, int n) {
    int i = blockIdx.x * blockDim.x + threadIdx.x;
    if (i < n) dis[i] = 1.0f / sqrtf((float)(cnt[i] + 1));  // +1 self loop, deg>=1
}

// block-level exclusive scan (256/block) + block sums
__global__ void scan1_kernel(const int* __restrict__ cnt, int* __restrict__ offs,
                             int* __restrict__ bsum, int n) {
    __shared__ int s[256];
    int i = blockIdx.x * 256 + threadIdx.x;
    int c = (i < n) ? cnt[i] : 0;
    s[threadIdx.x] = c;
    __syncthreads();
    for (int d = 1; d < 256; d <<= 1) {
        int t = 0;
        if ((int)threadIdx.x >= d) t = s[threadIdx.x - d];
        __syncthreads();
        if ((int)threadIdx.x >= d) s[threadIdx.x] += t;
        __syncthreads();
    }
    if (i < n) offs[i] = s[threadIdx.x] - c;  // exclusive
    if (threadIdx.x == 255) bsum[blockIdx.x] = s[255];
}

// parallel exclusive scan of the 196 block sums (single 256-thread block)
__global__ void scan2_kernel(int* __restrict__ bsum, int nb) {
    __shared__ int s[256];
    int t = threadIdx.x;
    int v = (t < nb) ? bsum[t] : 0;
    s[t] = v;
    __syncthreads();
    for (int d = 1; d < 256; d <<= 1) {
        int u = 0;
        if (t >= d) u = s[t - d];
        __syncthreads();
        if (t >= d) s[t] += u;
        __syncthreads();
    }
    if (t < nb) bsum[t] = s[t] - v;  // exclusive
}

__global__ void scan3_kernel(int* __restrict__ offs, const int* __restrict__ bsum,
                             int* __restrict__ cursor, int n) {
    int i = blockIdx.x * 256 + threadIdx.x;   // blockDim must be 256
    if (i < n) { int o = offs[i] + bsum[i >> 8]; offs[i] = o; cursor[i] = o; }
}

__global__ void fill_kernel(const int* __restrict__ src, const int* __restrict__ dst,
                            int* __restrict__ cursor, int* __restrict__ csr_src, int e) {
    int i = blockIdx.x * blockDim.x + threadIdx.x;
    if (i < e) {
        int p = atomicAdd(&cursor[dst[i]], 1);
        csr_src[p] = src[i];
    }
}

// ---------------- fp32 tiled GEMM: C[M,N] = A[M,K] @ B[K,N] ----------------
// BM=128, BN=64, BK=32, 256 threads, 8x4 microtile.
// Requires: N % 64 == 0, K % 32 == 0. M guarded.
// BR: fused bias + relu epilogue.

template<bool BR>
__global__ __launch_bounds__(256) void gemm_kernel(
        const float* __restrict__ A, const float* __restrict__ B,
        const float* __restrict__ bias, float* __restrict__ C,
        int M, int N, int K) {
    __shared__ float As[32][132];   // transposed A tile: As[k][m], stride 132 keeps 16B align
    __shared__ float Bs[32][68];    // Bs[k][n]
    int tid = threadIdx.x;
    int brow = blockIdx.x * 128;
    int bcol = blockIdx.y * 64;
    int tx = tid & 15;              // 16 columns of 4
    int ty = tid >> 4;              // 16 rows of 8
    float acc[8][4] = {};

    for (int k0 = 0; k0 < K; k0 += 32) {
        #pragma unroll
        for (int p = 0; p < 4; p++) {
            int r = (tid >> 3) + p * 32;        // 0..127
            int kk = (tid & 7) * 4;             // 0,4,..28
            int row = brow + r;
            float4 v = make_float4(0.f, 0.f, 0.f, 0.f);
            if (row < M) v = *(const float4*)&A[(size_t)row * K + k0 + kk];
            As[kk + 0][r] = v.x;
            As[kk + 1][r] = v.y;
            As[kk + 2][r] = v.z;
            As[kk + 3][r] = v.w;
        }
        #pragma unroll
        for (int p = 0; p < 2; p++) {
            int idx = p * 1024 + tid * 4;
            int kk = idx >> 6;                  // 0..31
            int c = idx & 63;
            *(float4*)&Bs[kk][c] = *(const float4*)&B[(size_t)(k0 + kk) * N + bcol + c];
        }
        __syncthreads();
        #pragma unroll
        for (int kk = 0; kk < 32; kk++) {
            float a[8], b[4];
            *(float4*)&a[0] = *(const float4*)&As[kk][ty * 8];
            *(float4*)&a[4] = *(const float4*)&As[kk][ty * 8 + 4];
            *(float4*)&b[0] = *(const float4*)&Bs[kk][tx * 4];
            #pragma unroll
            for (int i = 0; i < 8; i++)
                #pragma unroll
                for (int j = 0; j < 4; j++) acc[i][j] += a[i] * b[j];
        }
        __syncthreads();
    }

    float bv[4];
    #pragma unroll
    for (int j = 0; j < 4; j++) bv[j] = BR ? bias[bcol + tx * 4 + j] : 0.f;
    #pragma unroll
    for (int i = 0; i < 8; i++) {
        int row = brow + ty * 8 + i;
        if (row < M) {
            float4 r;
            float t0 = acc[i][0], t1 = acc[i][1], t2 = acc[i][2], t3 = acc[i][3];
            if (BR) {
                t0 = fmaxf(t0 + bv[0], 0.f);
                t1 = fmaxf(t1 + bv[1], 0.f);
                t2 = fmaxf(t2 + bv[2], 0.f);
                t3 = fmaxf(t3 + bv[3], 0.f);
            }
            r.x = t0; r.y = t1; r.z = t2; r.w = t3;
            *(float4*)&C[(size_t)row * N + bcol + tx * 4] = r;
        }
    }
}

// ---------------- aggregation: out[v] = sum_in h[u]*dis[u]*dis[v] + h[v]*dis[v]^2 (+ b, relu) ----
// one wave per node, lane holds VPT consecutive features (float2 for F=128).
// 4-edge batched main loop: 4 independent index->weight->gather chains in flight.

template<int F, bool RELU, bool BIAS>
__global__ void aggregate_kernel(const float* __restrict__ xw,
                                 float* __restrict__ out,
                                 const float* __restrict__ dis,
                                 const int* __restrict__ starts,
                                 const int* __restrict__ ends,
                                 const int* __restrict__ csr_src,
                                 const float* __restrict__ bias,
                                 int n) {
    int wave = (blockIdx.x * blockDim.x + threadIdx.x) >> 6;
    int lane = threadIdx.x & 63;
    if (wave >= n) return;
    int v = wave;
    constexpr int VPT = F / 64;  // consecutive floats per lane
    float dv = dis[v];
    float acc[VPT];
    {
        const float* r = &xw[(size_t)v * F + lane * VPT];
        #pragma unroll
        for (int i = 0; i < VPT; i++) acc[i] = r[i] * dv * dv;
    }
    int s = starts[v], e = ends[v];
    int p = s;
    for (; p + 4 <= e; p += 4) {
        int u0 = csr_src[p + 0];
        int u1 = csr_src[p + 1];
        int u2 = csr_src[p + 2];
        int u3 = csr_src[p + 3];
        float w0 = dis[u0] * dv;
        float w1 = dis[u1] * dv;
        float w2 = dis[u2] * dv;
        float w3 = dis[u3] * dv;
        const float* r0 = &xw[(size_t)u0 * F + lane * VPT];
        const float* r1 = &xw[(size_t)u1 * F + lane * VPT];
        const float* r2 = &xw[(size_t)u2 * F + lane * VPT];
        const float* r3 = &xw[(size_t)u3 * F + lane * VPT];
        if constexpr (VPT == 2) {
            float2 g0 = *(const float2*)r0;
            float2 g1 = *(const float2*)r1;
            float2 g2 = *(const float2*)r2;
            float2 g3 = *(const float2*)r3;
            acc[0] += g0.x * w0; acc[1] += g0.y * w0;
            acc[0] += g1.x * w1; acc[1] += g1.y * w1;
            acc[0] += g2.x * w2; acc[1] += g2.y * w2;
            acc[0] += g3.x * w3; acc[1] += g3.y * w3;
        } else {
            float g0 = *r0, g1 = *r1, g2 = *r2, g3 = *r3;
            acc[0] += g0 * w0;
            acc[0] += g1 * w1;
            acc[0] += g2 * w2;
            acc[0] += g3 * w3;
        }
    }
    for (; p < e; p++) {
        int u = csr_src[p];
        float w = dis[u] * dv;
        const float* r = &xw[(size_t)u * F + lane * VPT];
        #pragma unroll
        for (int i = 0; i < VPT; i++) acc[i] += r[i] * w;
    }
    {
        float* o = &out[(size_t)v * F + lane * VPT];
        #pragma unroll
        for (int i = 0; i < VPT; i++) {
            float r = acc[i];
            if (BIAS) r += bias[lane * VPT + i];
            if (RELU) r = fmaxf(r, 0.f);
            o[i] = r;
        }
    }
}

// ---------------- edge dot products: out[e] = h[i0] . h[i1], F=64 ----------------
// thread-per-edge, float4 x 16 per row, fully independent loads.

__global__ void dot_kernel(const float* __restrict__ h,
                           const int* __restrict__ pos, const int* __restrict__ neg,
                           float* __restrict__ out) {
    int t = blockIdx.x * blockDim.x + threadIdx.x;
    if (t >= E_POS + E_NEG) return;
    int i0, i1;
    if (t < E_POS) { i0 = pos[t]; i1 = pos[E_POS + t]; }
    else { int e = t - E_POS; i0 = neg[e]; i1 = neg[E_NEG + e]; }
    const float4* a = (const float4*)&h[(size_t)i0 * 64];
    const float4* b = (const float4*)&h[(size_t)i1 * 64];
    float s0 = 0.f, s1 = 0.f, s2 = 0.f, s3 = 0.f;
    #pragma unroll
    for (int k = 0; k < 16; k += 4) {
        float4 a0 = a[k + 0], a1 = a[k + 1], a2 = a[k + 2], a3 = a[k + 3];
        float4 b0 = b[k + 0], b1 = b[k + 1], b2 = b[k + 2], b3 = b[k + 3];
        s0 += a0.x * b0.x + a0.y * b0.y + a0.z * b0.z + a0.w * b0.w;
        s1 += a1.x * b1.x + a1.y * b1.y + a1.z * b1.z + a1.w * b1.w;
        s2 += a2.x * b2.x + a2.y * b2.y + a2.z * b2.z + a2.w * b2.w;
        s3 += a3.x * b3.x + a3.y * b3.y + a3.z * b3.z + a3.w * b3.w;
    }
    out[t] = (s0 + s1) + (s2 + s3);
}

// ---------------- launch ----------------

extern "C" void kernel_launch(void* const* d_in, const int* in_sizes, int n_in,
                              void* d_out, int out_size, void* d_ws, size_t ws_size,
                              hipStream_t stream) {
    const float* x  = (const float*)d_in[0];
    const int* tei  = (const int*)d_in[1];
    const int* pos  = (const int*)d_in[2];
    const int* neg  = (const int*)d_in[3];
    const float* W1 = (const float*)d_in[4];
    const float* b1 = (const float*)d_in[5];
    const float* W2 = (const float*)d_in[6];
    const float* b2 = (const float*)d_in[7];
    const float* W3 = (const float*)d_in[8];
    const float* b3 = (const float*)d_in[9];
    float* out = (float*)d_out;

    const int* src = tei;
    const int* dst = tei + E_TRAIN;

    char* ws = (char*)d_ws;
    size_t off = 0;
    auto alloc = [&](size_t bytes) -> void* {
        void* p = ws + off;
        off = (off + bytes + 255) & ~(size_t)255;
        return p;
    };
    float* bufA = (float*)alloc((size_t)N_NODES * 128 * 4);  // aggX / xw2 / xw3
    float* bufB = (float*)alloc((size_t)N_NODES * 256 * 4);  // h1, later h3
    float* bufC = (float*)alloc((size_t)N_NODES * 128 * 4);  // h2
    float* dis  = (float*)alloc(N_NODES * 4);
    int* cnt    = (int*)alloc(N_NODES * 4);
    int* offs   = (int*)alloc(N_NODES * 4);
    int* cursor = (int*)alloc(N_NODES * 4);
    int* bsum   = (int*)alloc(256 * 4);
    int* csr    = (int*)alloc((size_t)E_TRAIN * 4);
    (void)ws_size; (void)n_in; (void)in_sizes; (void)out_size;

    hipMemsetAsync(cnt, 0, N_NODES * 4, stream);
    count_kernel<<<(E_TRAIN + 255) / 256, 256, 0, stream>>>(dst, cnt, E_TRAIN);
    dis_kernel<<<(N_NODES + 255) / 256, 256, 0, stream>>>(cnt, dis, N_NODES);
    int nb = (N_NODES + 255) / 256;  // 196
    scan1_kernel<<<nb, 256, 0, stream>>>(cnt, offs, bsum, N_NODES);
    scan2_kernel<<<1, 256, 0, stream>>>(bsum, nb);
    scan3_kernel<<<nb, 256, 0, stream>>>(offs, bsum, cursor, N_NODES);
    fill_kernel<<<(E_TRAIN + 255) / 256, 256, 0, stream>>>(src, dst, cursor, csr, E_TRAIN);
    // after fill: offs[v] = start, cursor[v] = end

    const int MB = (N_NODES + 127) / 128;     // 391 row tiles
    const int AGG_BLOCKS = (N_NODES + 3) / 4; // 4 waves/block, 1 node/wave

    // layer 1 (agg-first): aggX = agg(x) [F=128]; h1 = relu(aggX @ W1 + b1) [256]
    aggregate_kernel<128, false, false><<<AGG_BLOCKS, 256, 0, stream>>>(
        x, bufA, dis, offs, cursor, csr, nullptr, N_NODES);
    gemm_kernel<true><<<dim3(MB, 4), 256, 0, stream>>>(
        bufA, W1, b1, bufB, N_NODES, 256, 128);

    // layer 2 (gemm-first): xw2 = h1 @ W2 [128]; h2 = relu(agg(xw2) + b2)
    gemm_kernel<false><<<dim3(MB, 2), 256, 0, stream>>>(
        bufB, W2, nullptr, bufA, N_NODES, 128, 256);
    aggregate_kernel<128, true, true><<<AGG_BLOCKS, 256, 0, stream>>>(
        bufA, bufC, dis, offs, cursor, csr, b2, N_NODES);

    // layer 3 (gemm-first): xw3 = h2 @ W3 [64]; h3 = agg(xw3) + b3
    gemm_kernel<false><<<dim3(MB, 1), 256, 0, stream>>>(
        bufC, W3, nullptr, bufA, N_NODES, 64, 128);
    aggregate_kernel<64, false, true><<<AGG_BLOCKS, 256, 0, stream>>>(
        bufA, bufB, dis, offs, cursor, csr, b3, N_NODES);

    // edge dots over h3 (64 features)
    dot_kernel<<<(E_POS + E_NEG + 255) / 256, 256, 0, stream>>>(bufB, pos, neg, out);
}